// Round 6
// baseline (1256.930 us; speedup 1.0000x reference)
//
#include <hip/hip_runtime.h>
#include <math.h>

#define B_ 32
#define L_ 336
#define C_ 321
#define P_ 96
#define E_ 4
#define H_ 2048
#define BC_ (B_*C_)          // 10272
#define INVc 0.99999500003749969f   // 1/sqrt(1+1e-5)

typedef __attribute__((ext_vector_type(8))) _Float16 f16x8;
typedef __attribute__((ext_vector_type(16))) float f32x16;
typedef __attribute__((ext_vector_type(2))) int v2i;

// Inline gelu via A&S 7.1.26 erf approximation (|err| ~1.5e-7, all VALU, no calls).
// Replaces erff() which caused ABI register saves -> scratch spills in hot kernels.
__device__ __forceinline__ float gelu_f(float x) {
    float ax = fabsf(x) * 0.70710678118654752440f;
    float t = 1.0f / (1.0f + 0.3275911f * ax);
    float poly = t * (0.254829592f + t * (-0.284496736f +
                 t * (1.421413741f + t * (-1.453152027f + t * 1.061405429f))));
    float e = __expf(-ax * ax);
    float erfv = 1.0f - poly * e;
    erfv = (x < 0.f) ? -erfv : erfv;
    return 0.5f * x * (1.0f + erfv);
}

__device__ __forceinline__ unsigned packh(float a, float b) {
    _Float16 ha = (_Float16)a, hb = (_Float16)b;
    unsigned short ua = __builtin_bit_cast(unsigned short, ha);
    unsigned short ub = __builtin_bit_cast(unsigned short, hb);
    return (unsigned)ua | ((unsigned)ub << 16);
}

// ---------------- zero out ----------------
__global__ void k_zero(float* __restrict__ p, int n) {
    int i = blockIdx.x * blockDim.x + threadIdx.x;
    if (i < n) p[i] = 0.f;
}

// ---------------- BN1 + transpose + pyramid pooling (coalesced) ----------------
__global__ __launch_bounds__(256) void k_bnpool(
    const float* __restrict__ x, const float* __restrict__ bw, const float* __restrict__ bb,
    float* __restrict__ h, float* __restrict__ s0, float* __restrict__ s1, float* __restrict__ s2)
{
    __shared__ float t[16][337];
    __shared__ float p2[16][168];
    __shared__ float p1[16][84];
    const int b = blockIdx.y;
    const int c0 = blockIdx.x * 16;
    const int tid = threadIdx.x;
    {
        const int tl = tid >> 4, tc = tid & 15;
        const int c = c0 + tc;
        for (int l0 = 0; l0 < L_; l0 += 16) {
            int l = l0 + tl;
            float v = (c < C_) ? x[((size_t)b * L_ + l) * C_ + c] : 0.f;
            t[tc][l] = v;
        }
    }
    __syncthreads();
    for (int idx = tid; idx < 16 * L_; idx += 256) {
        int tt = idx / L_, l = idx - tt * L_;
        int c = c0 + tt;
        if (c < C_) {
            float v = t[tt][l] * (bw[c * L_ + l] * INVc) + bb[c * L_ + l];
            t[tt][l] = v;
            h[(size_t)(b * C_ + c) * L_ + l] = v;
        }
    }
    __syncthreads();
    for (int idx = tid; idx < 16 * 168; idx += 256) {
        int tt = idx / 168, i = idx - tt * 168;
        int c = c0 + tt;
        float v = 0.5f * (t[tt][2 * i] + t[tt][2 * i + 1]);
        p2[tt][i] = v;
        if (c < C_) s2[(size_t)(b * C_ + c) * 168 + i] = v;
    }
    __syncthreads();
    for (int idx = tid; idx < 16 * 84; idx += 256) {
        int tt = idx / 84, i = idx - tt * 84;
        int c = c0 + tt;
        float v = 0.5f * (p2[tt][2 * i] + p2[tt][2 * i + 1]);
        p1[tt][i] = v;
        if (c < C_) s1[(size_t)(b * C_ + c) * 84 + i] = v;
    }
    __syncthreads();
    for (int idx = tid; idx < 16 * 42; idx += 256) {
        int tt = idx / 42, i = idx - tt * 42;
        int c = c0 + tt;
        float v = 0.5f * (p1[tt][2 * i] + p1[tt][2 * i + 1]);
        if (c < C_) s0[(size_t)(b * C_ + c) * 42 + i] = v;
    }
}

// ---------------- generic guarded GEMM (mixer, fp32); optional fused BN2 ----------------
template<int GELU, int ADD, int BN2>
__global__ __launch_bounds__(256) void gemm_kernel(
    const float* __restrict__ A, const float* __restrict__ W,
    const float* __restrict__ bias, const float* __restrict__ S,
    float* __restrict__ D, int M, int N, int K,
    const float* __restrict__ bnw, const float* __restrict__ bnb, float* __restrict__ D2)
{
    __shared__ __align__(16) float As[16][68];
    __shared__ __align__(16) float Ws[16][68];
    int m0 = blockIdx.x * 64, n0 = blockIdx.y * 64;
    int tid = threadIdx.x;
    int tr = tid >> 4, tc = tid & 15;
    float acc[4][4];
    #pragma unroll
    for (int i = 0; i < 4; ++i)
        #pragma unroll
        for (int j = 0; j < 4; ++j) acc[i][j] = 0.f;

    int nk = (K + 15) >> 4;
    for (int kt = 0; kt < nk; ++kt) {
        int k0 = kt * 16;
        #pragma unroll
        for (int it = 0; it < 4; ++it) {
            int elem = tid + it * 256;
            int row = elem >> 4, kk = elem & 15;
            int gm = m0 + row, gk = k0 + kk;
            As[kk][row] = (gm < M && gk < K) ? A[(size_t)gm * K + gk] : 0.f;
            int gn = n0 + row;
            Ws[kk][row] = (gn < N && gk < K) ? W[(size_t)gn * K + gk] : 0.f;
        }
        __syncthreads();
        #pragma unroll
        for (int kk = 0; kk < 16; ++kk) {
            float4 a4 = *reinterpret_cast<const float4*>(&As[kk][tr * 4]);
            float4 w4 = *reinterpret_cast<const float4*>(&Ws[kk][tc * 4]);
            float av[4] = {a4.x, a4.y, a4.z, a4.w};
            float wv[4] = {w4.x, w4.y, w4.z, w4.w};
            #pragma unroll
            for (int i = 0; i < 4; ++i)
                #pragma unroll
                for (int j = 0; j < 4; ++j) acc[i][j] += av[i] * wv[j];
        }
        __syncthreads();
    }
    #pragma unroll
    for (int i = 0; i < 4; ++i) {
        int m = m0 + tr * 4 + i;
        if (m >= M) continue;
        int cch = 0;
        if (BN2) cch = m % C_;
        #pragma unroll
        for (int j = 0; j < 4; ++j) {
            int n = n0 + tc * 4 + j;
            if (n >= N) continue;
            float v = acc[i][j] + bias[n];
            if (GELU) v = gelu_f(v);
            if (ADD) v += S[(size_t)m * N + n];
            D[(size_t)m * N + n] = v;
            if (BN2) {
                D2[(size_t)m * N + n] = v * (bnw[cch * N + n] * INVc) + bnb[cch * N + n];
            }
        }
    }
}

// ---------------- DDI scan -> planar fp16 hi/lo planes [tok][336] ----------------
__global__ __launch_bounds__(256) void k_ddi(
    const float* __restrict__ d, const float* __restrict__ n1w, const float* __restrict__ n1b,
    const float* __restrict__ aggw, const float* __restrict__ aggb,
    ushort* __restrict__ ahi, ushort* __restrict__ alo)
{
    __shared__ float sAw[144];
    __shared__ float sAb[12];
    int tid = threadIdx.x;
    if (tid < 144) sAw[tid] = aggw[tid];
    if (tid < 12) sAb[tid] = aggb[tid];
    __syncthreads();
    int token = blockIdx.x * blockDim.x + tid;
    if (token >= BC_) return;
    int c = token % C_;
    float w[12], bb[12], prev[12];
    #pragma unroll
    for (int p = 0; p < 12; ++p) { w[p] = n1w[c * 12 + p] * INVc; bb[p] = n1b[c * 12 + p]; }
    const float* drow = d + (size_t)token * L_;
    unsigned* hrow = (unsigned*)(ahi + (size_t)token * L_);
    unsigned* lrow = (unsigned*)(alo + (size_t)token * L_);

    auto store12 = [&](int base, const float* v) {
        #pragma unroll
        for (int j = 0; j < 6; ++j) {
            float v0 = v[2*j], v1 = v[2*j+1];
            float h0 = (float)(_Float16)v0, h1 = (float)(_Float16)v1;
            hrow[(base >> 1) + j] = packh(v0, v1);
            lrow[(base >> 1) + j] = packh(v0 - h0, v1 - h1);
        }
    };

    #pragma unroll
    for (int p = 0; p < 12; ++p) prev[p] = drow[p];
    store12(0, prev);
    for (int t = 0; t < 27; ++t) {
        float inp[12];
        #pragma unroll
        for (int p = 0; p < 12; ++p) inp[p] = prev[p] * w[p] + bb[p];
        float o[12];
        #pragma unroll
        for (int i = 0; i < 12; ++i) {
            float a = sAb[i];
            #pragma unroll
            for (int p = 0; p < 12; ++p) a += inp[p] * sAw[i * 12 + p];
            o[i] = gelu_f(a);
        }
        const float* xp = drow + 12 + t * 12;
        #pragma unroll
        for (int p = 0; p < 12; ++p) prev[p] = o[p] + xp[p];
        store12(12 + t * 12, prev);
    }
}

// ---------------- gating (wave per token, coalesced; stays fp32) ----------------
__global__ __launch_bounds__(256) void k_gate(
    const float* __restrict__ te, const float* __restrict__ gw,
    const float* __restrict__ gb, float* __restrict__ gates)
{
    __shared__ float gw_s[4][L_];
    int tid = threadIdx.x;
    for (int idx = tid; idx < 4 * L_; idx += 256) gw_s[idx / L_][idx - (idx / L_) * L_] = gw[idx];
    __syncthreads();
    int wv = tid >> 6, lane = tid & 63;
    int token = blockIdx.x * 4 + wv;
    if (token >= BC_) return;
    const float* row = te + (size_t)token * L_;
    float a0 = 0.f, a1 = 0.f, a2 = 0.f, a3 = 0.f;
    for (int l = lane; l < L_; l += 64) {
        float tv = row[l];
        a0 += tv * gw_s[0][l]; a1 += tv * gw_s[1][l];
        a2 += tv * gw_s[2][l]; a3 += tv * gw_s[3][l];
    }
    #pragma unroll
    for (int off = 32; off > 0; off >>= 1) {
        a0 += __shfl_down(a0, off);
        a1 += __shfl_down(a1, off);
        a2 += __shfl_down(a2, off);
        a3 += __shfl_down(a3, off);
    }
    if (lane == 0) {
        float acc[4] = {a0 + gb[0], a1 + gb[1], a2 + gb[2], a3 + gb[3]};
        int im = 0;
        #pragma unroll
        for (int e = 1; e < 4; ++e) if (acc[e] > acc[im]) im = e;
        float second = -1e30f;
        #pragma unroll
        for (int e = 0; e < 4; ++e) if (e != im) second = fmaxf(second, acc[e]);
        float mx = acc[im];
        float s[4]; float ssum = 0.f;
        #pragma unroll
        for (int e = 0; e < 4; ++e) { s[e] = expf(acc[e] - mx); ssum += s[e]; }
        float dec[4]; float dmx = -1e30f;
        #pragma unroll
        for (int e = 0; e < 4; ++e) {
            s[e] /= ssum;
            dec[e] = (acc[e] < second) ? 10.f * logf(s[e] + 1.f) : 10.f * (expf(s[e]) - 1.f);
            dmx = fmaxf(dmx, dec[e]);
        }
        float g[4]; float gsum = 0.f;
        #pragma unroll
        for (int e = 0; e < 4; ++e) { g[e] = expf(dec[e] - dmx); gsum += g[e]; }
        #pragma unroll
        for (int e = 0; e < 4; ++e) gates[token * 4 + e] = g[e] / gsum;
    }
}

// ---------------- pack w1 -> fp16 MFMA-A-operand frags [e][hb64][ks21][lane][8] ----------------
__global__ __launch_bounds__(256) void k_packw1(const float* __restrict__ ew1, uint4* __restrict__ w1f)
{
    int idx = blockIdx.x * 256 + threadIdx.x;   // < 4*64*21*64
    int lane = idx & 63;
    int q = idx >> 6;
    int ks = q % 21;
    int q2 = q / 21;
    int hb = q2 & 63;
    int e = q2 >> 6;
    int row = e * 2048 + hb * 32 + (lane & 31);
    int k = ks * 16 + 8 * (lane >> 5);
    const float* src = ew1 + (size_t)row * L_ + k;
    float4 f0 = *(const float4*)src;
    float4 f1 = *(const float4*)(src + 4);
    uint4 o;
    o.x = packh(f0.x, f0.y); o.y = packh(f0.z, f0.w);
    o.z = packh(f1.x, f1.y); o.w = packh(f1.z, f1.w);
    w1f[idx] = o;
}

// ---------------- pack w2 -> fp16 MFMA-B-operand frags [e][pt3][ks128][lane][8] ----------------
__global__ __launch_bounds__(256) void k_packw2(const float* __restrict__ ew2, uint4* __restrict__ w2f)
{
    int idx = blockIdx.x * 256 + threadIdx.x;   // < 4*3*128*64
    int lane = idx & 63;
    int q = idx >> 6;
    int ks2 = q % 128;
    int q2 = q / 128;
    int pt = q2 % 3;
    int e = q2 / 3;
    int row = e * 96 + pt * 32 + (lane & 31);
    int k = ks2 * 16 + 8 * (lane >> 5);
    const float* src = ew2 + (size_t)row * H_ + k;
    float4 f0 = *(const float4*)src;
    float4 f1 = *(const float4*)(src + 4);
    uint4 o;
    o.x = packh(f0.x, f0.y); o.y = packh(f0.z, f0.w);
    o.z = packh(f1.x, f1.y); o.w = packh(f1.z, f1.w);
    w2f[idx] = o;
}

// ---------------- fused expert MLP: fp16 2-term, swapped GEMM1, permlane GEMM2 ----------------
// grid 648: expert pinned to XCD pair. 512 thr = 8 waves = 2 token-halves x 4 h-slices.
// Per wave: 32 tokens x 512 h, acc1 split per fp16-plane (4 indep MFMA chains), acc2 = 3 tiles.
// Register budget: acc1 64 + acc2 48 + temps -> no spills (the round-5 killer).
__global__ __launch_bounds__(512, 2) void k_expert_mfma(
    const ushort* __restrict__ ahi, const ushort* __restrict__ alo,
    const uint4* __restrict__ w1f, const float* __restrict__ eb1,
    const uint4* __restrict__ w2f, const float* __restrict__ eb2,
    const float* __restrict__ gates, float* __restrict__ out)
{
    __shared__ union {
        uint4 a[2 * 42 * 64];        // [pl][g42][tok64] 16B frags, 86016 B
        float red[64 * 96];          // epilogue reduce
    } sm;

    const int bid = blockIdx.x;
    const int e = (bid & 7) >> 1;
    const int tile = ((bid >> 3) << 1) | (bid & 1);
    if (tile >= 161) return;
    const int t0 = tile * 64;

    const int tid = threadIdx.x;
    const int lane = tid & 63;
    const int wv = tid >> 6;
    const int th2 = wv & 1;          // token half (32 tokens)
    const int hsl = wv >> 1;         // h slice (512 h)
    const int l31 = lane & 31;
    const int u = lane >> 5;

    // ---- stage token planes into LDS (frag-packed, linear = conflict-free) ----
    #pragma unroll
    for (int it = 0; it < 11; ++it) {
        int gi = it * 8 + wv;
        if (gi < 84) {
            int pl = gi / 42, g = gi % 42, tok = lane;
            uint4 v = make_uint4(0u, 0u, 0u, 0u);
            if (t0 + tok < BC_) {
                const ushort* src = (pl ? alo : ahi) + (size_t)(t0 + tok) * L_ + g * 8;
                v = *(const uint4*)src;
            }
            sm.a[(pl * 42 + g) * 64 + tok] = v;
        }
    }
    __syncthreads();   // the only barrier before the epilogue

    const char* lbase = (const char*)sm.a;
    const int boffh = u * 1024 + th2 * 512 + l31 * 16;   // + ks*2048
    const int boffl = 43008 + boffh;

    const uint4* w1base = w1f + (size_t)e * 64 * 21 * 64;
    const uint4* w2base = w2f + (size_t)e * 3 * 128 * 64;

    f32x16 acc2[3];
    #pragma unroll
    for (int pt = 0; pt < 3; ++pt)
        #pragma unroll
        for (int r = 0; r < 16; ++r) acc2[pt][r] = 0.f;

    for (int sw = 0; sw < 8; ++sw) {
        const int hb0 = hsl * 16 + sw * 2;

        f32x16 a1h0, a1l0, a1h1, a1l1;
        #pragma unroll
        for (int r = 0; r < 16; ++r) { a1h0[r] = 0.f; a1l0[r] = 0.f; a1h1[r] = 0.f; a1l1[r] = 0.f; }

        // ---- GEMM1: C1^T[h][tok] = W1 . A^T, 2-term on token side ----
        for (int ks = 0; ks < 21; ++ks) {
            f16x8 wf0 = __builtin_bit_cast(f16x8, w1base[((size_t)hb0 * 21 + ks) * 64 + lane]);
            f16x8 wf1 = __builtin_bit_cast(f16x8, w1base[((size_t)(hb0 + 1) * 21 + ks) * 64 + lane]);
            f16x8 bh = __builtin_bit_cast(f16x8, *(const uint4*)(lbase + boffh + ks * 2048));
            f16x8 bl = __builtin_bit_cast(f16x8, *(const uint4*)(lbase + boffl + ks * 2048));
            a1h0 = __builtin_amdgcn_mfma_f32_32x32x16_f16(wf0, bh, a1h0, 0, 0, 0);
            a1l0 = __builtin_amdgcn_mfma_f32_32x32x16_f16(wf0, bl, a1l0, 0, 0, 0);
            a1h1 = __builtin_amdgcn_mfma_f32_32x32x16_f16(wf1, bh, a1h1, 0, 0, 0);
            a1l1 = __builtin_amdgcn_mfma_f32_32x32x16_f16(wf1, bl, a1l1, 0, 0, 0);
        }

        // ---- bias + gelu + fp16 split + permlane -> GEMM2 ----
        #pragma unroll
        for (int m = 0; m < 2; ++m) {
            const int hb = hb0 + m;
            float g0[16];
            #pragma unroll
            for (int r = 0; r < 16; ++r) {
                float av = (m == 0) ? (a1h0[r] + a1l0[r]) : (a1h1[r] + a1l1[r]);
                float bv = eb1[e * H_ + hb * 32 + (r & 3) + 4 * u + 8 * (r >> 2)];
                g0[r] = gelu_f(av + bv);
            }
            #pragma unroll
            for (int kl = 0; kl < 2; ++kl) {
                const int ks2 = hb * 2 + kl;
                f16x8 w2frag[3];
                #pragma unroll
                for (int pt = 0; pt < 3; ++pt)
                    w2frag[pt] = __builtin_bit_cast(f16x8, w2base[((size_t)pt * 128 + ks2) * 64 + lane]);
                const float* vv = &g0[8 * kl];
                // hi plane
                unsigned X0 = packh(vv[0], vv[1]), X1 = packh(vv[2], vv[3]);
                unsigned Y0 = packh(vv[4], vv[5]), Y1 = packh(vv[6], vv[7]);
                v2i s0v = __builtin_amdgcn_permlane32_swap((int)X0, (int)Y0, false, false);
                v2i s1v = __builtin_amdgcn_permlane32_swap((int)X1, (int)Y1, false, false);
                uint4 fh;
                fh.x = (unsigned)s0v.x; fh.y = (unsigned)s1v.x;
                fh.z = (unsigned)s0v.y; fh.w = (unsigned)s1v.y;
                // lo plane (residual)
                float r0 = vv[0] - (float)(_Float16)vv[0];
                float r1 = vv[1] - (float)(_Float16)vv[1];
                float r2 = vv[2] - (float)(_Float16)vv[2];
                float r3 = vv[3] - (float)(_Float16)vv[3];
                float r4 = vv[4] - (float)(_Float16)vv[4];
                float r5 = vv[5] - (float)(_Float16)vv[5];
                float r6 = vv[6] - (float)(_Float16)vv[6];
                float r7 = vv[7] - (float)(_Float16)vv[7];
                unsigned Xl0 = packh(r0, r1), Xl1 = packh(r2, r3);
                unsigned Yl0 = packh(r4, r5), Yl1 = packh(r6, r7);
                v2i s2v = __builtin_amdgcn_permlane32_swap((int)Xl0, (int)Yl0, false, false);
                v2i s3v = __builtin_amdgcn_permlane32_swap((int)Xl1, (int)Yl1, false, false);
                uint4 fl;
                fl.x = (unsigned)s2v.x; fl.y = (unsigned)s3v.x;
                fl.z = (unsigned)s2v.y; fl.w = (unsigned)s3v.y;

                f16x8 fhv = __builtin_bit_cast(f16x8, fh);
                f16x8 flv = __builtin_bit_cast(f16x8, fl);
                #pragma unroll
                for (int pt = 0; pt < 3; ++pt) {
                    acc2[pt] = __builtin_amdgcn_mfma_f32_32x32x16_f16(fhv, w2frag[pt], acc2[pt], 0, 0, 0);
                    acc2[pt] = __builtin_amdgcn_mfma_f32_32x32x16_f16(flv, w2frag[pt], acc2[pt], 0, 0, 0);
                }
            }
        }
    }

    // ---- epilogue: 8-wave LDS reduce, then gate-weighted global atomics ----
    __syncthreads();
    for (int i = tid; i < 64 * 96; i += 512) sm.red[i] = 0.f;
    __syncthreads();
    #pragma unroll
    for (int pt = 0; pt < 3; ++pt)
        #pragma unroll
        for (int r = 0; r < 16; ++r) {
            int tl = th2 * 32 + (r & 3) + 4 * u + 8 * (r >> 2);
            int p = pt * 32 + l31;
            atomicAdd(&sm.red[tl * 96 + p], acc2[pt][r]);
        }
    __syncthreads();
    for (int i = tid; i < 64 * 96; i += 512) {
        int tl = i / 96, p = i - tl * 96;
        int tok = t0 + tl;
        if (tok < BC_) {
            float gv = gates[tok * 4 + e];
            int b = tok / C_, c = tok - (tok / C_) * C_;
            atomicAdd(&out[((size_t)b * P_ + p) * C_ + c], gv * (sm.red[i] + eb2[e * P_ + p]));
        }
    }
}

// ---------------- launch ----------------
extern "C" void kernel_launch(void* const* d_in, const int* in_sizes, int n_in,
                              void* d_out, int out_size, void* d_ws, size_t ws_size,
                              hipStream_t stream) {
    const float* x       = (const float*)d_in[0];
    const float* mdm_w   = (const float*)d_in[2];
    const float* mdm_b   = (const float*)d_in[3];
    const float* m0w1    = (const float*)d_in[4];
    const float* m0b1    = (const float*)d_in[5];
    const float* m0w2    = (const float*)d_in[6];
    const float* m0b2    = (const float*)d_in[7];
    const float* m1w1    = (const float*)d_in[8];
    const float* m1b1    = (const float*)d_in[9];
    const float* m1w2    = (const float*)d_in[10];
    const float* m1b2    = (const float*)d_in[11];
    const float* m2w1    = (const float*)d_in[12];
    const float* m2b1    = (const float*)d_in[13];
    const float* m2w2    = (const float*)d_in[14];
    const float* m2b2    = (const float*)d_in[15];
    const float* dbn_w   = (const float*)d_in[16];
    const float* dbn_b   = (const float*)d_in[17];
    const float* n1w     = (const float*)d_in[18];
    const float* n1b     = (const float*)d_in[19];
    const float* agg_w   = (const float*)d_in[20];
    const float* agg_b   = (const float*)d_in[21];
    const float* gate_w  = (const float*)d_in[22];
    const float* gate_b  = (const float*)d_in[23];
    const float* ew1     = (const float*)d_in[24];
    const float* eb1     = (const float*)d_in[25];
    const float* ew2     = (const float*)d_in[26];
    const float* eb2     = (const float*)d_in[27];
    float* out = (float*)d_out;

    float* ws = (float*)d_ws;
    float* h    = ws;                           // 336*BC fp32 (te)
    float* s0   = ws + (size_t)336 * BC_;       // 42*BC
    float* s1   = ws + (size_t)378 * BC_;       // 84*BC
    float* s2   = ws + (size_t)462 * BC_;       // 168*BC  (later: w2f)
    float* gbuf = ws + (size_t)630 * BC_;       // 168*BC  (later: w1f)
    float* dbuf = ws + (size_t)798 * BC_;       // 336*BC
    float* gates= ws + (size_t)1134 * BC_;      // 4*BC

    ushort* ahi = (ushort*)ws;                  // BC*336 fp16 (overlays h, after k_gate)
    ushort* alo = ahi + (size_t)BC_ * L_;
    uint4* w2f = (uint4*)s2;                    // 4*3*128*64 frags = 1.57 MB
    uint4* w1f = (uint4*)gbuf;                  // 4*64*21*64 frags = 5.5 MB

    const int OUTN = B_ * P_ * C_;
    k_zero<<<(OUTN + 255) / 256, 256, 0, stream>>>(out, OUTN);
    k_bnpool<<<dim3(21, 32), 256, 0, stream>>>(x, mdm_w, mdm_b, h, s0, s1, s2);

    gemm_kernel<1,0,0><<<dim3(161,1), 256, 0, stream>>>(s0,   m0w1, m0b1, nullptr, gbuf, BC_, 42,  42,  nullptr, nullptr, nullptr);
    gemm_kernel<0,1,0><<<dim3(161,2), 256, 0, stream>>>(gbuf, m0w2, m0b2, s1,      s1,   BC_, 84,  42,  nullptr, nullptr, nullptr);
    gemm_kernel<1,0,0><<<dim3(161,2), 256, 0, stream>>>(s1,   m1w1, m1b1, nullptr, gbuf, BC_, 84,  84,  nullptr, nullptr, nullptr);
    gemm_kernel<0,1,0><<<dim3(161,3), 256, 0, stream>>>(gbuf, m1w2, m1b2, s2,      s2,   BC_, 168, 84,  nullptr, nullptr, nullptr);
    gemm_kernel<1,0,0><<<dim3(161,3), 256, 0, stream>>>(s2,   m2w1, m2b1, nullptr, gbuf, BC_, 168, 168, nullptr, nullptr, nullptr);
    // s2 free now -> pack w2 into it
    k_packw2<<<(E_*3*128*64) / 256, 256, 0, stream>>>(ew2, w2f);
    // final mixer GEMM with fused BN2 (te -> h, d -> dbuf)
    gemm_kernel<0,1,1><<<dim3(161,6), 256, 0, stream>>>(gbuf, m2w2, m2b2, h,       h,    BC_, 336, 168, dbn_w, dbn_b, dbuf);
    // gbuf free now -> pack w1 into it
    k_packw1<<<(E_*64*21*64) / 256, 256, 0, stream>>>(ew1, w1f);

    k_gate<<<(BC_ + 3) / 4, 256, 0, stream>>>(h, gate_w, gate_b, gates);
    // h free now -> ddi writes fp16 planes over it
    k_ddi<<<(BC_ + 255) / 256, 256, 0, stream>>>(dbuf, n1w, n1b, agg_w, agg_b, ahi, alo);

    k_expert_mfma<<<648, 512, 0, stream>>>(ahi, alo, w1f, eb1, w2f, eb2, gates, out);
}